// Round 2
// baseline (150.881 us; speedup 1.0000x reference)
//
#include <hip/hip_runtime.h>

#define NSTEP 64
#define HDIM 1024
#define BDIM 2048
#define OHH 511

typedef float v2f __attribute__((ext_vector_type(2)));

__device__ __forceinline__ v2f vsplat(float s) { v2f r; r.x = s; r.y = s; return r; }

// Wave-level DPP lane shifts (single VALU op; proven exact + neutral-cost).
// bound_ctrl=false: edge lane keeps own value; both edge uses are multiplied
// by 0 (identity rotations), so this is exact.
__device__ __forceinline__ float dpp_up1(float v) {   // lane n <- lane n-1
    int i = __builtin_bit_cast(int, v);
    int r = __builtin_amdgcn_update_dpp(i, i, 0x138, 0xF, 0xF, false);  // wave_shr:1
    return __builtin_bit_cast(float, r);
}
__device__ __forceinline__ float dpp_dn1(float v) {   // lane n <- lane n+1
    int i = __builtin_bit_cast(int, v);
    int r = __builtin_amdgcn_update_dpp(i, i, 0x130, 0xF, 0xF, false);  // wave_shl:1
    return __builtin_bit_cast(float, r);
}

// Async global->LDS DMA, 16 B per active lane. LDS dest is the wave-uniform
// base (HW adds lane*16); global src is per-lane.
__device__ __forceinline__ void stage16(const float4* g, const float4* l) {
    __builtin_amdgcn_global_load_lds(
        (const __attribute__((address_space(1))) void*)g,
        (__attribute__((address_space(3))) void*)l,
        16, 0, 0);
}

// ---------------------------------------------------------------------------
// Kernel 1: transposed coefficient tables (champion layout).
//   etab[s*512 + ((p&7)<<6|(p>>3))] (c,sn,sp,cp): even pair p, cols 2p,2p+1
//   otab same for odd pair j (cols 2j+1,2j+2); j==511 -> identity pad
//   wtab[q][lane] float4 = (cw0,sw0,cw1,sw1) for cols (16*lane+2q, +2q+1)
// Transposed order => lane-stride-16B (conflict-free) reads both from global
// and from the LDS copy (LDS is staged as a byte-identical slice).
// ---------------------------------------------------------------------------
__global__ void coeff_kernel(const float* __restrict__ omega,
                             const float* __restrict__ ETh,
                             const float* __restrict__ OTh,
                             const float* __restrict__ EPh,
                             const float* __restrict__ OPh,
                             float4* __restrict__ etab,
                             float4* __restrict__ otab,
                             float2* __restrict__ wtab)
{
    int idx = blockIdx.x * 256 + threadIdx.x;
    if (idx < NSTEP * 512) {
        int p = idx & 511;
        float c, s, cp, sp;
        __sincosf(ETh[idx], &s, &c);
        __sincosf(EPh[idx], &sp, &cp);
        etab[(idx & ~511) | ((p & 7) << 6) | (p >> 3)] = make_float4(c, s, sp, cp);
    } else if (idx < 2 * NSTEP * 512) {
        int i2 = idx - NSTEP * 512;
        int l = i2 >> 9;
        int j = i2 & 511;
        float4 v;
        if (j < OHH) {
            float c, s, cp, sp;
            __sincosf(OTh[l * OHH + j], &s, &c);
            __sincosf(OPh[l * OHH + j], &sp, &cp);
            v = make_float4(c, s, sp, cp);
        } else {
            v = make_float4(1.f, 0.f, 1.f, 0.f);  // identity rotation
        }
        otab[(i2 & ~511) | ((j & 7) << 6) | (j >> 3)] = v;
    } else if (idx < 2 * NSTEP * 512 + HDIM) {
        int c = idx - 2 * NSTEP * 512;
        float cw, sw;
        __sincosf(omega[c], &sw, &cw);
        int p = c >> 1;
        wtab[(((p & 7) << 6) | (p >> 3)) * 2 + (c & 1)] = make_float2(cw, sw);
    }
}

// Packed complex pair rotation: state A,B are (re,im) v2f; f = (c,sn,sp,cp).
//   t = c*A - sn*B;  B' = c*B + sn*A;  A' = (sp + i*cp) * t
__device__ __forceinline__ void pair_rot(const float4 f, v2f& A, v2f& B) {
    v2f C = vsplat(f.x), S = vsplat(f.y);
    v2f t = C * A - S * B;
    B = C * B + S * A;
    v2f cps; cps.x = -f.w; cps.y = f.w;
    A = vsplat(f.z) * t + cps * t.yx;
}
// Right-boundary variant: update A only, Bn is neighbor's value.
__device__ __forceinline__ void pair_rot_a(const float4 f, v2f& A, const v2f Bn) {
    v2f t = vsplat(f.x) * A - vsplat(f.y) * Bn;
    v2f cps; cps.x = -f.w; cps.y = f.w;
    A = vsplat(f.z) * t + cps * t.yx;
}

// ---------------------------------------------------------------------------
// Kernel 2: champion math body (wave = 2 rows, full H per wave, DPP boundary
// exchange — NO cross-wave state traffic) + block-shared LDS coefficient
// staging. Diagnosis: the champion was coefficient-delivery bound — 68 KB/CU
// /step through one L1 (~1088 cyc) with exposed L2 latency, vs a 768-cyc
// VALU floor. All 4 waves of a block read the SAME 16 KB step slice, so we
// stage it once per block via global_load_lds (4 issues/wave/step, 0 VGPR),
// double-buffered. The per-step __syncthreads only gates wave-uniform coeff
// data (unlike R1's edge exchange, no state dependency crosses the barrier);
// its vmcnt(0) drain is exactly the wait the staged load needs, issued a
// full step (~800 cyc) earlier. Coeff reads become guaranteed-hit
// ds_read_b128 at lane-stride-16B (conflict-free), 544 cyc/CU/step in the
// LDS pipe — below the VALU floor.
// ---------------------------------------------------------------------------
__global__ __launch_bounds__(256, 1) void eunn_kernel(
    const float* __restrict__ x_re,
    const float* __restrict__ x_im,
    const float4* __restrict__ etab,
    const float4* __restrict__ otab,
    const float4* __restrict__ wtab,
    float* __restrict__ out)
{
    const int lane = threadIdx.x & 63;
    const int wave = threadIdx.x >> 6;
    const int row0 = blockIdx.x * 8 + wave * 2;
    const int colbase = lane << 4;
    const int lanem1 = (lane + 63) & 63;   // oc0 slot: k=7 row of lane-1 (lane0 -> j=511 identity)

    // [parity][ 0..511 = even slice | 512..1023 = odd slice ]  (32 KB)
    __shared__ float4 cbuf[2][1024];

    // stage step-s 16 KB slice into cbuf[buf]; each wave DMAs 4x1 KB chunks
    auto stage_slice = [&](int s, int buf) {
        const float4* ge = etab + s * 512 + wave * 64 + lane;
        const float4* go = otab + s * 512 + wave * 64 + lane;
        float4* d = &cbuf[buf][wave * 64];
        stage16(ge,       d);
        stage16(ge + 256, d + 256);
        stage16(go,       d + 512);
        stage16(go + 256, d + 768);
    };

    v2f x[2][16];   // interleaved (re, im) state

    // prologue: kick off step-0 coefficients before touching x
    stage_slice(0, 0);

    // --- load state (f32 planes), interleave into v2f regs ---
    #pragma unroll
    for (int r = 0; r < 2; ++r) {
        const float4* pr = reinterpret_cast<const float4*>(x_re + (row0 + r) * HDIM + colbase);
        const float4* pi = reinterpret_cast<const float4*>(x_im + (row0 + r) * HDIM + colbase);
        #pragma unroll
        for (int q = 0; q < 4; ++q) {
            float4 vr = pr[q];
            float4 vi = pi[q];
            x[r][4*q+0].x = vr.x; x[r][4*q+0].y = vi.x;
            x[r][4*q+1].x = vr.y; x[r][4*q+1].y = vi.y;
            x[r][4*q+2].x = vr.z; x[r][4*q+2].y = vi.z;
            x[r][4*q+3].x = vr.w; x[r][4*q+3].y = vi.w;
        }
    }

    __syncthreads();   // step-0 slice resident

    for (int s = 0; s < NSTEP; ++s) {
        const int par = s & 1;

        // issue next step's DMA first — it drains at this step's barrier
        if (s + 1 < NSTEP) stage_slice(s + 1, par ^ 1);

        // coefficient reads: guaranteed LDS hits, lane-stride 16 B
        const float4* cb = cbuf[par];
        float4 oc0 = cb[512 + (7 << 6) + lanem1];
        float4 ec[8], oc[8];
        #pragma unroll
        for (int k = 0; k < 8; ++k) ec[k] = cb[(k << 6) + lane];
        #pragma unroll
        for (int k = 0; k < 8; ++k) oc[k] = cb[512 + (k << 6) + lane];

        // ---- even layer, boundary pairs first (k=0,7)
        pair_rot(ec[0], x[0][0],  x[0][1]);
        pair_rot(ec[0], x[1][0],  x[1][1]);
        pair_rot(ec[7], x[0][14], x[0][15]);
        pair_rot(ec[7], x[1][14], x[1][15]);

        // boundary exchange on post-even values via DPP (VALU, ~2 cyc each)
        v2f xn[2], xl[2];
        #pragma unroll
        for (int r = 0; r < 2; ++r) {
            xn[r].x = dpp_dn1(x[r][0].x);    // right neighbor's col0
            xn[r].y = dpp_dn1(x[r][0].y);
            xl[r].x = dpp_up1(x[r][15].x);   // left neighbor's col15
            xl[r].y = dpp_up1(x[r][15].y);
        }

        // remaining even pairs k=1..6
        #pragma unroll
        for (int k = 1; k < 7; ++k) {
            pair_rot(ec[k], x[0][2*k], x[0][2*k+1]);
            pair_rot(ec[k], x[1][2*k], x[1][2*k+1]);
        }

        // ---- odd layer: internal pairs oc[k-1] -> local cols (2k-1, 2k)
        #pragma unroll
        for (int k = 1; k < 8; ++k) {
            pair_rot(oc[k-1], x[0][2*k-1], x[0][2*k]);
            pair_rot(oc[k-1], x[1][2*k-1], x[1][2*k]);
        }
        // right boundary (our col15 = "a", neighbor col0 = "b"): update col15
        // (lane63: oc[7] is identity pad, sn=0 -> xn value irrelevant)
        pair_rot_a(oc[7], x[0][15], xn[0]);
        pair_rot_a(oc[7], x[1][15], xn[1]);
        // left boundary (left col15 = "a", our col0 = "b"): update col0
        // (lane0: oc0 is j=511 identity pad, sn=0 -> xl value irrelevant)
        {
            v2f C = vsplat(oc0.x), S = vsplat(oc0.y);
            x[0][0] = C * x[0][0] + S * xl[0];
            x[1][0] = C * x[1][0] + S * xl[1];
        }

        // one barrier per step: drains the s+1 DMA (vmcnt) and republishes
        // cbuf[par] for overwrite at step s+2. No state crosses this barrier.
        __syncthreads();
    }

    // --- omega phase + de-interleave + store (coalesced) ---
    float4 wc[8];
    #pragma unroll
    for (int q = 0; q < 8; ++q) wc[q] = wtab[(q << 6) + lane];  // (cw0,sw0,cw1,sw1) cols 2q,2q+1

    #pragma unroll
    for (int r = 0; r < 2; ++r) {
        float4* pre = reinterpret_cast<float4*>(out + (row0 + r) * HDIM + colbase);
        float4* pim = reinterpret_cast<float4*>(out + BDIM * HDIM + (row0 + r) * HDIM + colbase);
        #pragma unroll
        for (int h = 0; h < 4; ++h) {
            float4 wa = wc[2*h];      // cols 4h, 4h+1
            float4 wb = wc[2*h + 1];  // cols 4h+2, 4h+3
            v2f X0 = x[r][4*h+0], X1 = x[r][4*h+1], X2 = x[r][4*h+2], X3 = x[r][4*h+3];
            float4 vr, vi;
            vr.x = X0.x * wa.x - X0.y * wa.y;  vi.x = X0.x * wa.y + X0.y * wa.x;
            vr.y = X1.x * wa.z - X1.y * wa.w;  vi.y = X1.x * wa.w + X1.y * wa.z;
            vr.z = X2.x * wb.x - X2.y * wb.y;  vi.z = X2.x * wb.y + X2.y * wb.x;
            vr.w = X3.x * wb.z - X3.y * wb.w;  vi.w = X3.x * wb.w + X3.y * wb.z;
            pre[h] = vr;
            pim[h] = vi;
        }
    }
}

extern "C" void kernel_launch(void* const* d_in, const int* in_sizes, int n_in,
                              void* d_out, int out_size, void* d_ws, size_t ws_size,
                              hipStream_t stream)
{
    const float* x_re  = (const float*)d_in[0];
    const float* x_im  = (const float*)d_in[1];
    const float* omega = (const float*)d_in[2];
    const float* eth   = (const float*)d_in[3];
    const float* oth   = (const float*)d_in[4];
    const float* eph   = (const float*)d_in[5];
    const float* oph   = (const float*)d_in[6];

    char* ws = (char*)d_ws;
    float4* etab = (float4*)ws;                             // 512 KB
    float4* otab = (float4*)(ws + NSTEP * 512 * 16);        // 512 KB
    float2* wtab = (float2*)(ws + 2 * NSTEP * 512 * 16);    // 8 KB

    coeff_kernel<<<260, 256, 0, stream>>>(omega, eth, oth, eph, oph, etab, otab, wtab);
    eunn_kernel<<<BDIM / 8, 256, 0, stream>>>(x_re, x_im, etab, otab,
                                              (const float4*)wtab, (float*)d_out);
}

// Round 3
// 127.103 us; speedup vs baseline: 1.1871x; 1.1871x over previous
//
#include <hip/hip_runtime.h>

#define NSTEP 64
#define HDIM 1024
#define BDIM 2048
#define OHH 511

typedef float v2f __attribute__((ext_vector_type(2)));

__device__ __forceinline__ v2f vsplat(float s) { v2f r; r.x = s; r.y = s; return r; }

// Wave-level DPP lane shifts (single VALU op; proven exact + neutral-cost).
// bound_ctrl=false: edge lane keeps own value; both edge uses are multiplied
// by 0 (identity rotations), so this is exact.
__device__ __forceinline__ float dpp_up1(float v) {   // lane n <- lane n-1
    int i = __builtin_bit_cast(int, v);
    int r = __builtin_amdgcn_update_dpp(i, i, 0x138, 0xF, 0xF, false);  // wave_shr:1
    return __builtin_bit_cast(float, r);
}
__device__ __forceinline__ float dpp_dn1(float v) {   // lane n <- lane n+1
    int i = __builtin_bit_cast(int, v);
    int r = __builtin_amdgcn_update_dpp(i, i, 0x130, 0xF, 0xF, false);  // wave_shl:1
    return __builtin_bit_cast(float, r);
}

// ---------------------------------------------------------------------------
// Kernel 1: transposed coefficient tables (champion layout, unchanged).
//   etab[s][k][lane] (float4 c,sn,sp,cp): even pair p = 8*lane+k, cols 2p,2p+1
//   otab same for odd pair j = 8*lane+k (cols 2j+1,2j+2); j==511 -> identity
//   wtab[q][lane] float4 = (cw0,sw0,cw1,sw1) for cols (16*lane+2q, +2q+1)
// ---------------------------------------------------------------------------
__global__ void coeff_kernel(const float* __restrict__ omega,
                             const float* __restrict__ ETh,
                             const float* __restrict__ OTh,
                             const float* __restrict__ EPh,
                             const float* __restrict__ OPh,
                             float4* __restrict__ etab,
                             float4* __restrict__ otab,
                             float2* __restrict__ wtab)
{
    int idx = blockIdx.x * 256 + threadIdx.x;
    if (idx < NSTEP * 512) {
        int p = idx & 511;
        float c, s, cp, sp;
        __sincosf(ETh[idx], &s, &c);
        __sincosf(EPh[idx], &sp, &cp);
        etab[(idx & ~511) | ((p & 7) << 6) | (p >> 3)] = make_float4(c, s, sp, cp);
    } else if (idx < 2 * NSTEP * 512) {
        int i2 = idx - NSTEP * 512;
        int l = i2 >> 9;
        int j = i2 & 511;
        float4 v;
        if (j < OHH) {
            float c, s, cp, sp;
            __sincosf(OTh[l * OHH + j], &s, &c);
            __sincosf(OPh[l * OHH + j], &sp, &cp);
            v = make_float4(c, s, sp, cp);
        } else {
            v = make_float4(1.f, 0.f, 1.f, 0.f);  // identity rotation
        }
        otab[(i2 & ~511) | ((j & 7) << 6) | (j >> 3)] = v;
    } else if (idx < 2 * NSTEP * 512 + HDIM) {
        int c = idx - 2 * NSTEP * 512;
        float cw, sw;
        __sincosf(omega[c], &sw, &cw);
        int p = c >> 1;
        wtab[(((p & 7) << 6) | (p >> 3)) * 2 + (c & 1)] = make_float2(cw, sw);
    }
}

// Packed complex pair rotation: state A,B are (re,im) v2f; f = (c,sn,sp,cp).
//   t = c*A - sn*B;  B' = c*B + sn*A;  A' = (sp + i*cp) * t
__device__ __forceinline__ void pair_rot(const float4 f, v2f& A, v2f& B) {
    v2f C = vsplat(f.x), S = vsplat(f.y);
    v2f t = C * A - S * B;
    B = C * B + S * A;
    v2f cps; cps.x = -f.w; cps.y = f.w;
    A = vsplat(f.z) * t + cps * t.yx;
}
// Right-boundary variant: update A only, Bn is neighbor's value.
__device__ __forceinline__ void pair_rot_a(const float4 f, v2f& A, const v2f Bn) {
    v2f t = vsplat(f.x) * A - vsplat(f.y) * Bn;
    v2f cps; cps.x = -f.w; cps.y = f.w;
    A = vsplat(f.z) * t + cps * t.yx;
}

// ---------------------------------------------------------------------------
// Kernel 2: champion math body (wave = 2 rows, full H, DPP boundaries, NO
// barrier, NO LDS) + FORCED full software pipeline of all 17 coefficient
// loads one step ahead.
//
// Diagnosis across R0-R2: champion's 2212 cyc/step ~= VALU(995) + L1(1088)
// SERIALIZED — VGPR_Count 80 proves the compiler sinks coefficient loads to
// just before use (recycling registers), exposing delivery time every step.
// Both LDS attempts regressed (per-step barrier lockstep + same sink
// problem on ds_read). Fix: two named register sets (cur/nxt, 17 float4
// each), 2-step-unrolled loop, sched_barrier(0) after each prefetch block
// so loads cannot sink into their consuming step. Consumers are a full body
// (~800+ cyc) downstream -> wait becomes counted vmcnt with slack; per-step
// wall -> max(VALU, L1) ~= 1100 cyc instead of the sum.
// Tell: VGPR_Count must jump to ~200+. If it stays ~80, compiler won again.
// ---------------------------------------------------------------------------
__global__ __launch_bounds__(256, 1) void eunn_kernel(
    const float* __restrict__ x_re,
    const float* __restrict__ x_im,
    const float4* __restrict__ etab,
    const float4* __restrict__ otab,
    const float4* __restrict__ wtab,
    float* __restrict__ out)
{
    const int lane = threadIdx.x & 63;
    const int wave = threadIdx.x >> 6;
    const int row0 = blockIdx.x * 8 + wave * 2;
    const int colbase = lane << 4;
    const int lanem1 = (lane + 63) & 63;   // oc0 slot: k=7 row of lane-1 (lane0 -> identity)

    v2f x[2][16];   // interleaved (re, im) state

    // current / next step coefficient register sets (17 float4 each)
    float4 cec[8], coc[8], coc0;
    float4 nec[8], noc[8], noc0;

    // --- prologue: issue step-0 coefficient loads first (in flight under
    // the state loads below)
    {
        const float4* e = etab + lane;
        const float4* o = otab + lane;
        #pragma unroll
        for (int k = 0; k < 8; ++k) cec[k] = e[k << 6];
        #pragma unroll
        for (int k = 0; k < 8; ++k) coc[k] = o[k << 6];
        coc0 = otab[(7 << 6) + lanem1];
    }

    // --- load state (f32 planes), interleave into v2f regs ---
    #pragma unroll
    for (int r = 0; r < 2; ++r) {
        const float4* pr = reinterpret_cast<const float4*>(x_re + (row0 + r) * HDIM + colbase);
        const float4* pi = reinterpret_cast<const float4*>(x_im + (row0 + r) * HDIM + colbase);
        #pragma unroll
        for (int q = 0; q < 4; ++q) {
            float4 vr = pr[q];
            float4 vi = pi[q];
            x[r][4*q+0].x = vr.x; x[r][4*q+0].y = vi.x;
            x[r][4*q+1].x = vr.y; x[r][4*q+1].y = vi.y;
            x[r][4*q+2].x = vr.z; x[r][4*q+2].y = vi.z;
            x[r][4*q+3].x = vr.w; x[r][4*q+3].y = vi.w;
        }
    }

    // one full step's math with coefficient set (ec, oc, oc0)
    auto body = [&](const float4 (&ec)[8], const float4 (&oc)[8], const float4 oc0) {
        // ---- even layer, boundary pairs first (k=0,7)
        pair_rot(ec[0], x[0][0],  x[0][1]);
        pair_rot(ec[0], x[1][0],  x[1][1]);
        pair_rot(ec[7], x[0][14], x[0][15]);
        pair_rot(ec[7], x[1][14], x[1][15]);

        // boundary exchange on post-even values via DPP (VALU, ~2 cyc each)
        v2f xn[2], xl[2];
        #pragma unroll
        for (int r = 0; r < 2; ++r) {
            xn[r].x = dpp_dn1(x[r][0].x);    // right neighbor's col0
            xn[r].y = dpp_dn1(x[r][0].y);
            xl[r].x = dpp_up1(x[r][15].x);   // left neighbor's col15
            xl[r].y = dpp_up1(x[r][15].y);
        }

        // remaining even pairs k=1..6
        #pragma unroll
        for (int k = 1; k < 7; ++k) {
            pair_rot(ec[k], x[0][2*k], x[0][2*k+1]);
            pair_rot(ec[k], x[1][2*k], x[1][2*k+1]);
        }

        // ---- odd layer: internal pairs oc[k-1] -> local cols (2k-1, 2k)
        #pragma unroll
        for (int k = 1; k < 8; ++k) {
            pair_rot(oc[k-1], x[0][2*k-1], x[0][2*k]);
            pair_rot(oc[k-1], x[1][2*k-1], x[1][2*k]);
        }
        // right boundary (our col15 = "a", neighbor col0 = "b"): update col15
        // (lane63: oc[7] is identity pad, sn=0 -> xn value irrelevant)
        pair_rot_a(oc[7], x[0][15], xn[0]);
        pair_rot_a(oc[7], x[1][15], xn[1]);
        // left boundary (left col15 = "a", our col0 = "b"): update col0
        // (lane0: oc0 is identity, sn=0 -> xl value irrelevant)
        {
            v2f C = vsplat(oc0.x), S = vsplat(oc0.y);
            x[0][0] = C * x[0][0] + S * xl[0];
            x[1][0] = C * x[1][0] + S * xl[1];
        }
    };

    // 2-step unrolled main loop; every coefficient load issued one full step
    // before first use, pinned by sched_barrier so it cannot sink.
    for (int s = 0; s < NSTEP; s += 2) {
        {   // prefetch step s+1 -> n-set (consumed in second half)
            const float4* e = etab + (s + 1) * 512 + lane;
            const float4* o = otab + (s + 1) * 512 + lane;
            #pragma unroll
            for (int k = 0; k < 8; ++k) nec[k] = e[k << 6];
            #pragma unroll
            for (int k = 0; k < 8; ++k) noc[k] = o[k << 6];
            noc0 = (otab + (s + 1) * 512)[(7 << 6) + lanem1];
        }
        __builtin_amdgcn_sched_barrier(0);   // loads may not sink below
        body(cec, coc, coc0);

        {   // prefetch step s+2 -> c-set (clamped; last-iter loads unused but valid)
            int s2 = (s + 2 < NSTEP) ? (s + 2) : (NSTEP - 1);
            const float4* e = etab + s2 * 512 + lane;
            const float4* o = otab + s2 * 512 + lane;
            #pragma unroll
            for (int k = 0; k < 8; ++k) cec[k] = e[k << 6];
            #pragma unroll
            for (int k = 0; k < 8; ++k) coc[k] = o[k << 6];
            coc0 = (otab + s2 * 512)[(7 << 6) + lanem1];
        }
        __builtin_amdgcn_sched_barrier(0);   // loads may not sink below
        body(nec, noc, noc0);
    }

    // --- omega phase + de-interleave + store (coalesced) ---
    float4 wc[8];
    #pragma unroll
    for (int q = 0; q < 8; ++q) wc[q] = wtab[(q << 6) + lane];  // (cw0,sw0,cw1,sw1) cols 2q,2q+1

    #pragma unroll
    for (int r = 0; r < 2; ++r) {
        float4* pre = reinterpret_cast<float4*>(out + (row0 + r) * HDIM + colbase);
        float4* pim = reinterpret_cast<float4*>(out + BDIM * HDIM + (row0 + r) * HDIM + colbase);
        #pragma unroll
        for (int h = 0; h < 4; ++h) {
            float4 wa = wc[2*h];      // cols 4h, 4h+1
            float4 wb = wc[2*h + 1];  // cols 4h+2, 4h+3
            v2f X0 = x[r][4*h+0], X1 = x[r][4*h+1], X2 = x[r][4*h+2], X3 = x[r][4*h+3];
            float4 vr, vi;
            vr.x = X0.x * wa.x - X0.y * wa.y;  vi.x = X0.x * wa.y + X0.y * wa.x;
            vr.y = X1.x * wa.z - X1.y * wa.w;  vi.y = X1.x * wa.w + X1.y * wa.z;
            vr.z = X2.x * wb.x - X2.y * wb.y;  vi.z = X2.x * wb.y + X2.y * wb.x;
            vr.w = X3.x * wb.z - X3.y * wb.w;  vi.w = X3.x * wb.w + X3.y * wb.z;
            pre[h] = vr;
            pim[h] = vi;
        }
    }
}

extern "C" void kernel_launch(void* const* d_in, const int* in_sizes, int n_in,
                              void* d_out, int out_size, void* d_ws, size_t ws_size,
                              hipStream_t stream)
{
    const float* x_re  = (const float*)d_in[0];
    const float* x_im  = (const float*)d_in[1];
    const float* omega = (const float*)d_in[2];
    const float* eth   = (const float*)d_in[3];
    const float* oth   = (const float*)d_in[4];
    const float* eph   = (const float*)d_in[5];
    const float* oph   = (const float*)d_in[6];

    char* ws = (char*)d_ws;
    float4* etab = (float4*)ws;                             // 512 KB
    float4* otab = (float4*)(ws + NSTEP * 512 * 16);        // 512 KB
    float2* wtab = (float2*)(ws + 2 * NSTEP * 512 * 16);    // 8 KB

    coeff_kernel<<<260, 256, 0, stream>>>(omega, eth, oth, eph, oph, etab, otab, wtab);
    eunn_kernel<<<BDIM / 8, 256, 0, stream>>>(x_re, x_im, etab, otab,
                                              (const float4*)wtab, (float*)d_out);
}